// Round 2
// baseline (549.578 us; speedup 1.0000x reference)
//
#include <hip/hip_runtime.h>
#include <hip/hip_bf16.h>
#include <stdint.h>

#define N_ROWS 131072
#define D_IN   512
#define D_OUT  512
#define BM     64
#define BK     64
#define NKT    (D_IN / BK)   // 8
#define THREADS 512

typedef short s8v __attribute__((ext_vector_type(8)));   // 8 bf16 bits (4 VGPRs)
typedef float f4v __attribute__((ext_vector_type(4)));   // MFMA acc
typedef unsigned int u32;

// fp32 -> bf16 bits, round-to-nearest-even
__device__ __forceinline__ unsigned short f2bf(float f) {
    u32 b = __builtin_bit_cast(u32, f);
    b += 0x7FFFu + ((b >> 16) & 1u);
    return (unsigned short)(b >> 16);
}

// ---------------------------------------------------------------------------
// W fp32 [k][n] -> bf16 ws, transposed+tiled, plain [kt][n][k] layout:
//   ws[(kt*512 + n)*64 + kk] = bf16(W[(kt*64 + kk)*512 + n])
// B fragments are then read DIRECTLY from global (L2-resident, 512 KB):
// lane reads 8 consecutive k at n = n0 + (lane&15), k-off = ks*32+(lane>>4)*8.
// ---------------------------------------------------------------------------
__global__ void convert_w(const float* __restrict__ W, unsigned short* __restrict__ wsb) {
    int t = blockIdx.x * blockDim.x + threadIdx.x;   // 0 .. 262143
    int kk = t & 63;
    int n  = (t >> 6) & 511;
    int kt = t >> 15;
    wsb[t] = f2bf(W[(size_t)(kt * 64 + kk) * 512 + n]);
}

// ---------------------------------------------------------------------------
// GEMM: BM=64 rows/block, BN=512 (full D_OUT -> X read exactly once), BK=64.
// 512 threads = 8 waves; wave wv owns cols [wv*64, wv*64+64), 4x4 frags of
// 16x16x32 bf16 MFMA. LDS holds ONLY the A tile (2 x 64x72 bf16 = 18 KB,
// double-buffered, one barrier/iter). B frags come straight from L2.
// __launch_bounds__(512,4): VGPR<=128 -> 2 blocks/CU = 16 waves/CU, so one
// block's MFMA phase overlaps the other block's HBM streaming.
// ---------------------------------------------------------------------------
__global__ __launch_bounds__(THREADS, 4) void sparse_dense_gemm(
    const float* __restrict__ X, const unsigned short* __restrict__ Wb,
    const float* __restrict__ bias, float* __restrict__ Y)
{
    __shared__ unsigned short As[2][BM * 72];   // 72 = 64 + 8 pad (16B-aligned rows)

    const int tid  = threadIdx.x;
    const int lane = tid & 63;
    const int wv   = tid >> 6;          // 0..7
    const int r0   = blockIdx.x * BM;

    // A staging mapping: thread -> (row, k-group), global reads coalesced
    const int arow = tid >> 3;          // 0..63
    const int akg  = tid & 7;           // 0..7
    const float* xsrc = X + (size_t)(r0 + arow) * D_IN + akg * 8;

    const int c = lane & 15;            // frag col/row selector
    const int q = lane >> 4;            // quad 0..3

    // invariant part of this lane's B-frag address:
    // frag(kt,ks,nf) = Wb + kt*32768 + (wv*64 + nf*16 + c)*64 + ks*32 + q*8
    const unsigned short* bbase = Wb + (wv * 64 + c) * 64 + q * 8;

    f4v acc[4][4];
    #pragma unroll
    for (int mf = 0; mf < 4; ++mf)
        #pragma unroll
        for (int nf = 0; nf < 4; ++nf)
            acc[mf][nf] = f4v{0.f, 0.f, 0.f, 0.f};

    auto writeA = [&](float4 a0, float4 a1, int buf) {
        u32 w0 = (u32)f2bf(a0.x) | ((u32)f2bf(a0.y) << 16);
        u32 w1 = (u32)f2bf(a0.z) | ((u32)f2bf(a0.w) << 16);
        u32 w2 = (u32)f2bf(a1.x) | ((u32)f2bf(a1.y) << 16);
        u32 w3 = (u32)f2bf(a1.z) | ((u32)f2bf(a1.w) << 16);
        *(uint4*)(&As[buf][arow * 72 + akg * 8]) = make_uint4(w0, w1, w2, w3);
    };

    // prologue: stage kt=0 A tile
    float4 pa0 = *(const float4*)(xsrc);
    float4 pa1 = *(const float4*)(xsrc + 4);
    writeA(pa0, pa1, 0);

    int p = 0;
    for (int kt = 0; kt < NKT; ++kt) {
        __syncthreads();    // A buf p complete; buf p^1 free (readers done pre-barrier)
        if (kt + 1 < NKT) {  // issue next X loads now -> fly during MFMA phase
            pa0 = *(const float4*)(xsrc + (kt + 1) * BK);
            pa1 = *(const float4*)(xsrc + (kt + 1) * BK + 4);
        }
        const unsigned short* bk = bbase + kt * 32768;
        #pragma unroll
        for (int ks = 0; ks < 2; ++ks) {
            s8v bfr[4], af[4];
            #pragma unroll
            for (int nf = 0; nf < 4; ++nf)
                bfr[nf] = *(const s8v*)(bk + nf * 1024 + ks * 32);  // global, L2-hit
            #pragma unroll
            for (int mf = 0; mf < 4; ++mf)
                af[mf] = *(const s8v*)(&As[p][(mf * 16 + c) * 72 + ks * 32 + q * 8]);
            #pragma unroll
            for (int mf = 0; mf < 4; ++mf)
                #pragma unroll
                for (int nf = 0; nf < 4; ++nf)
                    acc[mf][nf] = __builtin_amdgcn_mfma_f32_16x16x32_bf16(
                        af[mf], bfr[nf], acc[mf][nf], 0, 0, 0);
        }
        if (kt + 1 < NKT) writeA(pa0, pa1, p ^ 1);
        p ^= 1;
    }

    // epilogue: C/D layout col=lane&15, row=(lane>>4)*4+i
    #pragma unroll
    for (int nf = 0; nf < 4; ++nf) {
        int col = wv * 64 + nf * 16 + c;
        float bv = bias[col];
        #pragma unroll
        for (int mf = 0; mf < 4; ++mf) {
            #pragma unroll
            for (int i = 0; i < 4; ++i) {
                int row = r0 + mf * 16 + q * 4 + i;
                Y[(size_t)row * D_OUT + col] = acc[mf][nf][i] + bv;
            }
        }
    }
}

extern "C" void kernel_launch(void* const* d_in, const int* in_sizes, int n_in,
                              void* d_out, int out_size, void* d_ws, size_t ws_size,
                              hipStream_t stream) {
    const float* X    = (const float*)d_in[0];
    const float* W    = (const float*)d_in[1];
    const float* bias = (const float*)d_in[2];
    float* Y          = (float*)d_out;
    unsigned short* wsb = (unsigned short*)d_ws;   // 512 KB bf16 W copy

    convert_w<<<1024, 256, 0, stream>>>(W, wsb);
    sparse_dense_gemm<<<N_ROWS / BM, THREADS, 0, stream>>>(X, wsb, bias, Y);
}